// Round 2
// 405.772 us; speedup vs baseline: 1.0177x; 1.0177x over previous
//
#include <hip/hip_runtime.h>

namespace {

constexpr float SCALE = 0.35355339059327373f;  // (1/sqrt(2))^3

typedef float fvec4 __attribute__((ext_vector_type(4)));  // nontemporal-OK vec

// x: (1024 rows, 65536) -> out: (1024 rows, 8 bands, 8192), Gray-code band order.
// Every 8 consecutive inputs produce one column in each of the 8 bands.
//
// Stage 0 (lane-local): float4 = 2 level-1 pairs -> level-2 {aa,ad,da,dd} halves.
// Stage 1 (shfl_xor 1): combine with neighbor lane -> each lane holds 4 band
//          values for ONE column: even lane slots {0,3,4,7}, odd {1,2,5,6}.
// Stage 2+3 (shfl_xor 4, shfl_xor 2): 4x4 register transpose across the four
//          same-parity lanes of each octet -> each lane holds ONE band slot for
//          FOUR consecutive columns -> single aligned 16B store per thread.
// Per wave: 8 bands x 128B fully-dense contiguous segments in ONE store instr.
__global__ __launch_bounds__(256) void wpt3_kernel(const float* __restrict__ x,
                                                   float* __restrict__ out) {
    const long long tid = (long long)blockIdx.x * 256 + threadIdx.x;
    const int lane_odd = (int)(tid & 1);

    // Coalesced, touch-once: nontemporal 16B load.
    const fvec4 v =
        __builtin_nontemporal_load(reinterpret_cast<const fvec4*>(x) + tid);

    // Level 1 (lane-local): 2 pairs.
    const float s0 = v.x + v.y, t0 = v.x - v.y;
    const float s1 = v.z + v.w, t1 = v.z - v.w;
    // Level 2 (lane-local): this lane holds half-group {aa,ad,da,dd}.
    const float p = s0 + s1;  // aa half
    const float q = s0 - s1;  // ad half
    const float r = t0 + t1;  // da half
    const float u = t0 - t1;  // dd half

    // Stage 1: level 3 via neighbor lane (other half of the 8-group).
    const float pp = __shfl_xor(p, 1, 64);
    const float qq = __shfl_xor(q, 1, 64);
    const float rr = __shfl_xor(r, 1, 64);
    const float uu = __shfl_xor(u, 1, 64);

    // Even lane: sum bands; odd lane: diff bands (slot^1).
    // Register i -> slot: even (0,3,4,7)[i], odd (1,2,5,6)[i].
    float b0 = (lane_odd ? (pp - p) : (p + pp)) * SCALE;  // slot 0 / 1
    float b1 = (lane_odd ? (qq - q) : (q + qq)) * SCALE;  // slot 3 / 2
    float b2 = (lane_odd ? (uu - u) : (u + uu)) * SCALE;  // slot 4 / 5
    float b3 = (lane_odd ? (rr - r) : (r + rr)) * SCALE;  // slot 7 / 6

    // 4x4 transpose across same-parity lanes of the octet.
    // j = position within the parity set = (lane>>1)&3; j bit1 -> lane xor 4,
    // j bit0 -> lane xor 2. Both stages preserve parity.
    const int lane = (int)(threadIdx.x & 63);
    const int jb1 = (lane >> 2) & 1;
    const int jb0 = (lane >> 1) & 1;

    // Stage 2 (xor 4): swap off-diagonal 2x2 blocks.
    {
        const float ta = jb1 ? b0 : b2;
        const float tb = jb1 ? b1 : b3;
        const float ra = __shfl_xor(ta, 4, 64);
        const float rb = __shfl_xor(tb, 4, 64);
        if (jb1 == 0) { b2 = ra; b3 = rb; } else { b0 = ra; b1 = rb; }
    }
    // Stage 3 (xor 2): transpose within each 2x2 block.
    {
        const float ta = jb0 ? b0 : b1;
        const float tb = jb0 ? b2 : b3;
        const float ra = __shfl_xor(ta, 2, 64);
        const float rb = __shfl_xor(tb, 2, 64);
        if (jb0 == 0) { b1 = ra; b3 = rb; } else { b0 = ra; b2 = rb; }
    }

    // Now lane (parity, j) holds band slot(j,parity) for cols [4*octet .. +4).
    // slot = 2*j + ((j&1) ^ parity):
    //   even: j=0..3 -> 0,3,4,7 ; odd: j=0..3 -> 1,2,5,6.
    const int j = (lane >> 1) & 3;
    const int slot = (j << 1) + ((j & 1) ^ lane_odd);

    const long long octet = tid >> 3;           // 4 groups (=cols) per octet
    const long long gbase = octet << 2;         // first col (global group idx)
    const int row = (int)(gbase >> 13);         // 8192 cols per row
    const int col = (int)(gbase & 8191);        // multiple of 4 -> 16B aligned

    fvec4 o;
    o.x = b0; o.y = b1; o.z = b2; o.w = b3;     // cols col..col+3 of `slot`
    fvec4* op = reinterpret_cast<fvec4*>(out + (long long)row * 65536 +
                                         (long long)slot * 8192 + col);
    __builtin_nontemporal_store(o, op);
}

}  // namespace

extern "C" void kernel_launch(void* const* d_in, const int* in_sizes, int n_in,
                              void* d_out, int out_size, void* d_ws, size_t ws_size,
                              hipStream_t stream) {
    const float* x = (const float*)d_in[0];
    float* out = (float*)d_out;
    // 67,108,864 floats / 4 per thread = 16,777,216 threads.
    dim3 grid(65536), block(256);
    hipLaunchKernelGGL(wpt3_kernel, grid, block, 0, stream, x, out);
}